// Round 1
// baseline (73.142 us; speedup 1.0000x reference)
//
#include <hip/hip_runtime.h>
#include <math.h>

#define NB 50

__device__ __forceinline__ float dev_rmax() {
    // matches Python: float(2.0 * sqrt(1.0 / (2.0 * sqrt(3.0) * 1024))), folded at compile time in double
    return (float)(2.0 * sqrt(1.0 / (2.0 * sqrt(3.0) * 1024.0)));
}

// One block = one wave = one a-disk. Lanes stride over b-disks.
__global__ void __launch_bounds__(64)
pcf_density_kernel(const float* __restrict__ da, const float* __restrict__ db,
                   const int* __restrict__ scp, float* __restrict__ dens,
                   int na, int nb)
{
    const float RMAX = dev_rmax();
    const float inv_rmax = 1.0f / RMAX;
    const int i   = blockIdx.x;
    const int tid = threadIdx.x;
    const int sc  = scp[0];

    // a-disk is wave-uniform -> scalar loads
    const float ax = da[3*i+0];
    const float ay = da[3*i+1];
    const float ar = da[3*i+2];

    float acc[NB];
#pragma unroll
    for (int b = 0; b < NB; ++b) acc[b] = 0.0f;

    for (int j = tid; j < nb; j += 64) {
        const float bx = db[3*j+0];
        const float by = db[3*j+1];
        const float br = db[3*j+2];
        const float dx = ax - bx;
        const float dy = ay - by;
        const float d  = sqrtf(dx*dx + dy*dy);
        const float r1 = fmaxf(ar, br);
        const float r2 = fminf(ar, br);
        const float extent  = fmaxf(d + r1 + r2, 2.0f*r1);
        const float overlap = fmaxf(r1 + r2 - d, 0.0f);
        const float dist = (extent - overlap + d + r1 - r2) * inv_rmax;
        // bins span rs/RMAX in [0.1, 5.0]; exp(-16 x^2) == 0 in f32 for |x| > ~2.55.
        // dist >= 7.5 -> every bin's term underflows to 0; skipping is exact to <1e-40.
        const bool skip = (sc != 0) && (j == i);
        if (dist < 7.5f && !skip) {
#pragma unroll
            for (int b = 0; b < NB; ++b) {
                const float x = 0.1f * (float)(b + 1) - dist;
                acc[b] += __expf(-16.0f * x * x);
            }
        }
    }

    // 64-lane -> per-bin reduction via LDS transpose. Stride 51 (odd) => conflict-free
    // writes (fixed b: addresses 51*t+b, 51 odd => bank permutation) and reads
    // (fixed t: lanes 0..49 consecutive).
    __shared__ float red[64 * 51];
#pragma unroll
    for (int b = 0; b < NB; ++b) red[tid * 51 + b] = acc[b];
    __syncthreads();

    if (tid < NB) {
        float s = 0.0f;
#pragma unroll 16
        for (int t = 0; t < 64; ++t) s += red[t * 51 + tid];

        const float PI = 3.14159265358979323846f;
        const float GF = 1.0f / (sqrtf(PI) * 0.25f);   // 1/(sqrt(pi)*SIGMA)
        const float rs = 0.1f * (float)(tid + 1) * RMAX;

        // perimeter weight for (disk i, bin tid)
        float full = 2.0f * PI;
        const float ex[4] = { ax, 1.0f - ax, ay, 1.0f - ay };
        const float ey[4] = { ay, ay,        ax, ax        };
#pragma unroll
        for (int c = 0; c < 4; ++c) {
            if (rs > ex[c]) {
                float ratio = ex[c] / rs;
                ratio = fminf(fmaxf(ratio, -1.0f), 1.0f);
                const float alpha = acosf(ratio);
                const float a1 = atan2f(ey[c], ex[c]);
                const float a2 = atan2f(1.0f - ey[c], ex[c]);
                full -= fminf(alpha, a1) + fminf(alpha, a2);
            }
        }
        float peri = full * (1.0f / (2.0f * PI));
        peri = fminf(fmaxf(peri, 0.0f), 1.0f);
        const float w = (peri > 0.0f) ? (1.0f / peri) : 0.0f;

        const float r_out = rs + 0.5f * RMAX;
        const float r_in  = fmaxf(rs - 0.5f * RMAX, 0.0f);
        const float area  = PI * (r_out * r_out - r_in * r_in);

        const float density = (GF * s) * w / area / (float)nb;
        dens[tid * na + i] = density;   // bin-major for coalesced reduction
    }
}

// One block per bin: mean / min / max over the 1024 a-disks.
__global__ void __launch_bounds__(64)
pcf_reduce_kernel(const float* __restrict__ dens, float* __restrict__ out, int na)
{
    const int b   = blockIdx.x;
    const int tid = threadIdx.x;
    const float RMAX = dev_rmax();

    float s = 0.0f, mn = INFINITY, mx = -INFINITY;
    for (int i = tid; i < na; i += 64) {
        const float v = dens[b * na + i];
        s  += v;
        mn  = fminf(mn, v);
        mx  = fmaxf(mx, v);
    }
#pragma unroll
    for (int off = 32; off >= 1; off >>= 1) {
        s  += __shfl_down(s, off);
        mn  = fminf(mn, __shfl_down(mn, off));
        mx  = fmaxf(mx, __shfl_down(mx, off));
    }
    if (tid == 0) {
        const float rs = 0.1f * (float)(b + 1) * RMAX;
        out[2*b + 0]  = rs / RMAX;     // pcf[:,0]
        out[2*b + 1]  = s / (float)na; // pcf[:,1] = mean
        out[100 + b]  = mn;            // pcf_lower
        out[150 + b]  = mx;            // pcf_upper
    }
}

extern "C" void kernel_launch(void* const* d_in, const int* in_sizes, int n_in,
                              void* d_out, int out_size, void* d_ws, size_t ws_size,
                              hipStream_t stream)
{
    const float* da = (const float*)d_in[0];
    const float* db = (const float*)d_in[1];
    const int*   sc = (const int*)d_in[2];
    float* out  = (float*)d_out;
    float* dens = (float*)d_ws;            // [NB][na] floats = 200 KB for na=1024
    const int na = in_sizes[0] / 3;
    const int nb = in_sizes[1] / 3;

    pcf_density_kernel<<<na, 64, 0, stream>>>(da, db, sc, dens, na, nb);
    pcf_reduce_kernel<<<NB, 64, 0, stream>>>(dens, out, na);
}

// Round 2
// 63.654 us; speedup vs baseline: 1.1491x; 1.1491x over previous
//
#include <hip/hip_runtime.h>
#include <math.h>

#define NB 50

__device__ __forceinline__ float dev_rmax() {
    // matches Python: float(2.0 * sqrt(1.0 / (2.0 * sqrt(3.0) * 1024))), folded in double
    return (float)(2.0 * sqrt(1.0 / (2.0 * sqrt(3.0) * 1024.0)));
}

// One block (256 threads = 4 waves) per a-disk.
// Phase 1 per 256-j round: all threads compute disk distance, ballot-compact the
// close ones (dist < 7.5, ~5%) into an LDS list.
// Phase 2: lane = bin; each wave walks its strided share of the list, 1 exp per
// (entry, bin). Heavy exp work thus scales with ACTUAL close pairs, not with
// wave-divergent worst case.
__global__ void __launch_bounds__(256)
pcf_density_kernel(const float* __restrict__ da, const float* __restrict__ db,
                   const int* __restrict__ scp, float* __restrict__ dens,
                   int na, int nb)
{
    const float RMAX = dev_rmax();
    const float inv_rmax = 1.0f / RMAX;
    const int i    = blockIdx.x;
    const int tid  = threadIdx.x;
    const int lane = tid & 63;
    const int wave = tid >> 6;
    const int sc   = scp[0];

    __shared__ float list[256];     // per-round close-dist list (capped by round size)
    __shared__ int   cnt;
    __shared__ float part[4 * NB];  // per-wave partial bin sums

    if (tid == 0) cnt = 0;
    __syncthreads();

    // a-disk is block-uniform -> scalar loads
    const float ax = da[3*i+0];
    const float ay = da[3*i+1];
    const float ar = da[3*i+2];

    const float binf = 0.1f * (float)(lane + 1);  // rs/RMAX for bin=lane (lanes>=50 masked later)
    float accb = 0.0f;

    for (int base = 0; base < nb; base += 256) {
        const int j = base + tid;
        bool close = false;
        float dist = 0.0f;
        if (j < nb) {
            const float bx = db[3*j+0];
            const float by = db[3*j+1];
            const float br = db[3*j+2];
            const float dx = ax - bx;
            const float dy = ay - by;
            const float d  = sqrtf(dx*dx + dy*dy);
            const float r1 = fmaxf(ar, br);
            const float r2 = fminf(ar, br);
            const float extent  = fmaxf(d + r1 + r2, 2.0f*r1);
            const float overlap = fmaxf(r1 + r2 - d, 0.0f);
            dist = (extent - overlap + d + r1 - r2) * inv_rmax;
            // exp(-16 x^2) underflows (f32) for |x|>2.55; bins span [0.1,5.0] ->
            // dist>=7.5 contributes < 1e-42 to any output. Safe to drop.
            close = (dist < 7.5f) && !((sc != 0) && (j == i));
        }
        // wave-level ballot compaction into the block list
        const unsigned long long m = __ballot(close);
        const int total  = __popcll(m);
        const int prefix = __popcll(m & ((1ull << lane) - 1ull));
        int wbase = 0;
        if (lane == 0) wbase = atomicAdd(&cnt, total);
        wbase = __shfl(wbase, 0);
        if (close) list[wbase + prefix] = dist;
        __syncthreads();

        // lane = bin; waves stride over the compacted list
        const int M = cnt;
        for (int k = wave; k < M; k += 4) {
            const float dl = list[k];          // broadcast read, conflict-free
            const float x  = binf - dl;
            accb += __expf(-16.0f * x * x);
        }
        __syncthreads();
        if (tid == 0) cnt = 0;
        __syncthreads();
    }

    if (lane < NB) part[wave * NB + lane] = accb;
    __syncthreads();

    if (wave == 0 && lane < NB) {
        const float s = part[lane] + part[NB + lane] + part[2*NB + lane] + part[3*NB + lane];

        const float PI = 3.14159265358979323846f;
        const float GF = 1.0f / (sqrtf(PI) * 0.25f);   // 1/(sqrt(pi)*SIGMA)
        const float rs = 0.1f * (float)(lane + 1) * RMAX;

        // perimeter weight for (disk i, bin lane)
        float full = 2.0f * PI;
        const float ex[4] = { ax, 1.0f - ax, ay, 1.0f - ay };
        const float ey[4] = { ay, ay,        ax, ax        };
#pragma unroll
        for (int c = 0; c < 4; ++c) {
            if (rs > ex[c]) {
                float ratio = ex[c] / rs;
                ratio = fminf(fmaxf(ratio, -1.0f), 1.0f);
                const float alpha = acosf(ratio);
                const float a1 = atan2f(ey[c], ex[c]);
                const float a2 = atan2f(1.0f - ey[c], ex[c]);
                full -= fminf(alpha, a1) + fminf(alpha, a2);
            }
        }
        float peri = full * (1.0f / (2.0f * PI));
        peri = fminf(fmaxf(peri, 0.0f), 1.0f);
        const float w = (peri > 0.0f) ? (1.0f / peri) : 0.0f;

        const float r_out = rs + 0.5f * RMAX;
        const float r_in  = fmaxf(rs - 0.5f * RMAX, 0.0f);
        const float area  = PI * (r_out * r_out - r_in * r_in);

        const float density = (GF * s) * w / area / (float)nb;
        dens[lane * na + i] = density;   // bin-major for coalesced reduction
    }
}

// One block (256 threads) per bin: mean / min / max over the na a-disks.
__global__ void __launch_bounds__(256)
pcf_reduce_kernel(const float* __restrict__ dens, float* __restrict__ out, int na)
{
    const int b    = blockIdx.x;
    const int tid  = threadIdx.x;
    const int lane = tid & 63;
    const int wave = tid >> 6;
    const float RMAX = dev_rmax();

    __shared__ float rs_[4], rmn[4], rmx[4];

    float s = 0.0f, mn = INFINITY, mx = -INFINITY;
    for (int i = tid; i < na; i += 256) {
        const float v = dens[b * na + i];
        s  += v;
        mn  = fminf(mn, v);
        mx  = fmaxf(mx, v);
    }
#pragma unroll
    for (int off = 32; off >= 1; off >>= 1) {
        s  += __shfl_down(s, off);
        mn  = fminf(mn, __shfl_down(mn, off));
        mx  = fmaxf(mx, __shfl_down(mx, off));
    }
    if (lane == 0) { rs_[wave] = s; rmn[wave] = mn; rmx[wave] = mx; }
    __syncthreads();
    if (tid == 0) {
        float ts = rs_[0] + rs_[1] + rs_[2] + rs_[3];
        float tmn = fminf(fminf(rmn[0], rmn[1]), fminf(rmn[2], rmn[3]));
        float tmx = fmaxf(fmaxf(rmx[0], rmx[1]), fmaxf(rmx[2], rmx[3]));
        const float rs = 0.1f * (float)(b + 1) * RMAX;
        out[2*b + 0] = rs / RMAX;       // pcf[:,0]
        out[2*b + 1] = ts / (float)na;  // pcf[:,1] = mean
        out[100 + b] = tmn;             // pcf_lower
        out[150 + b] = tmx;             // pcf_upper
    }
}

extern "C" void kernel_launch(void* const* d_in, const int* in_sizes, int n_in,
                              void* d_out, int out_size, void* d_ws, size_t ws_size,
                              hipStream_t stream)
{
    const float* da = (const float*)d_in[0];
    const float* db = (const float*)d_in[1];
    const int*   sc = (const int*)d_in[2];
    float* out  = (float*)d_out;
    float* dens = (float*)d_ws;            // [NB][na] floats = 200 KB for na=1024
    const int na = in_sizes[0] / 3;
    const int nb = in_sizes[1] / 3;

    pcf_density_kernel<<<na, 256, 0, stream>>>(da, db, sc, dens, na, nb);
    pcf_reduce_kernel<<<NB, 256, 0, stream>>>(dens, out, na);
}